// Round 8
// baseline (141.637 us; speedup 1.0000x reference)
//
#include <hip/hip_runtime.h>
#include <hip/hip_bf16.h>

#define N_NODES 100000
#define N_EDGES 1600000
#define D 128

#define NBINS 196       // ceil(100000 / 512)
#define BINSHIFT 9      // 512 nodes per bin
#define BINCAP 10000    // avg 8163 edges/bin
#define EPB 8192        // edges per bin-phase block

// k_mid block layout: [0,196) binsort, [196,204) W-frag build, [204,3329) X cvt
#define MID_SORT_BLOCKS 196
#define MID_W_BLOCKS 8
#define MID_CVT_BLOCKS 3125    // 100000*128 / (512*8)

#define PADK 136

typedef __bf16 bf16x8 __attribute__((ext_vector_type(8)));
typedef short short8 __attribute__((ext_vector_type(8)));
typedef float f32x4 __attribute__((ext_vector_type(4)));

__device__ __forceinline__ unsigned short f2bf(float f) {
  union { float f; unsigned u; } c; c.f = f;
  unsigned u = c.u;
  u += 0x7FFFu + ((u >> 16) & 1u);   // round-to-nearest-even
  return (unsigned short)(u >> 16);
}
__device__ __forceinline__ float bflo(unsigned u) {
  union { unsigned u; float f; } c; c.u = u << 16; return c.f;
}
__device__ __forceinline__ float bfhi(unsigned u) {
  union { unsigned u; float f; } c; c.u = u & 0xFFFF0000u; return c.f;
}

// ============ k_bin: edge binning; packs (dst&511)<<17 | src ================
__launch_bounds__(512)
__global__ void k_bin(const int* __restrict__ esrc, const int* __restrict__ edst,
                      int* __restrict__ g_bincnt, unsigned* __restrict__ binbuf) {
  __shared__ int cnt[NBINS];
  __shared__ int base[NBINS];
  const int b = blockIdx.x, t = threadIdx.x;
  const int e0 = b * EPB;
  const int ne = min(EPB, N_EDGES - e0);
  for (int i = t; i < NBINS; i += 512) cnt[i] = 0;
  __syncthreads();
  for (int i = t; i < ne; i += 512)
    atomicAdd(&cnt[edst[e0 + i] >> BINSHIFT], 1);
  __syncthreads();
  for (int i = t; i < NBINS; i += 512) {
    base[i] = atomicAdd(&g_bincnt[i], cnt[i]);
    cnt[i] = 0;
  }
  __syncthreads();
  for (int i = t; i < ne; i += 512) {
    int d = edst[e0 + i];
    int s = esrc[e0 + i];
    int bi = d >> BINSHIFT;
    int pos = base[bi] + atomicAdd(&cnt[bi], 1);
    binbuf[(size_t)bi * BINCAP + pos] = ((unsigned)(d & 511) << 17) | (unsigned)s;
  }
}

// ============ k_mid: fused binsort + W-frag build + X cvt ===================
// Wf layout (per matrix, 16384 bf16): Wf[((nc*4+kb)*64 + lane)*8 + e]
//   = W[(kb*32 + (lane>>4)*8 + e)*128 + nc*16 + (lane&15)]
// -> a wave's B-fragment load is one contiguous 1KB run.
__launch_bounds__(512)
__global__ void k_mid(const unsigned* __restrict__ binbuf, const int* __restrict__ g_bincnt,
                      int* __restrict__ srt, int* __restrict__ deg, int* __restrict__ offs,
                      const float* __restrict__ X, unsigned short* __restrict__ Xb,
                      const float* __restrict__ W1, const float* __restrict__ W2,
                      unsigned short* __restrict__ Wf) {
  const int b = blockIdx.x, t = threadIdx.x;

  if (b < MID_SORT_BLOCKS) {
    // ---- per-bin counting sort; emits deg/offs (START semantics) ----
    __shared__ int hist[512];
    __shared__ int scan[512];
    __shared__ int sb[256];
    if (t < 256) sb[t] = (t < NBINS) ? g_bincnt[t] : 0;
    __syncthreads();
    for (int d = 1; d < 256; d <<= 1) {
      int x = 0;
      if (t < 256 && t >= d) x = sb[t - d];
      __syncthreads();
      if (t < 256) sb[t] += x;
      __syncthreads();
    }
    const int cntb = g_bincnt[b];
    const int gbase = (b == 0) ? 0 : sb[b - 1];
    const int n0 = b << BINSHIFT;
    const unsigned* ebuf = binbuf + (size_t)b * BINCAP;

    hist[t] = 0;
    __syncthreads();
    for (int i = t; i < cntb; i += 512)
      atomicAdd(&hist[ebuf[i] >> 17], 1);
    __syncthreads();
    int v = hist[t];
    scan[t] = v;
    __syncthreads();
    for (int d = 1; d < 512; d <<= 1) {
      int x = (t >= d) ? scan[t - d] : 0;
      __syncthreads();
      scan[t] += x;
      __syncthreads();
    }
    int n = n0 + t;
    if (n < N_NODES) {
      deg[n] = v;
      offs[n] = gbase + scan[t] - v;   // segment start
    }
    hist[t] = scan[t] - v;             // bin-local write cursor
    __syncthreads();
    for (int i = t; i < cntb; i += 512) {
      unsigned e = ebuf[i];
      int pos = atomicAdd(&hist[e >> 17], 1);
      srt[gbase + pos] = (int)(e & 0x1FFFFu);
    }
    return;
  }
  if (b < MID_SORT_BLOCKS + MID_W_BLOCKS) {
    int bb = b - MID_SORT_BLOCKS;
#pragma unroll
    for (int it = 0; it < 8; ++it) {
      int idx = bb * 4096 + it * 512 + t;     // [0, 32768)
      int fi = idx & 16383;
      const float* W = (idx >> 14) ? W2 : W1;
      int e = fi & 7, l = (fi >> 3) & 63, q = fi >> 9;
      int kb = q & 3, nc = q >> 2;
      int k = kb * 32 + (l >> 4) * 8 + e;
      int n = nc * 16 + (l & 15);
      Wf[idx] = f2bf(W[k * 128 + n]);
    }
    return;
  }
  // ---- X f32 -> bf16 ----
  size_t i = ((size_t)(b - MID_SORT_BLOCKS - MID_W_BLOCKS) * 512 + t) * 8;
  const float4* p = (const float4*)(X + i);
  float4 a = p[0], c = p[1];
  short8 s;
  s[0] = f2bf(a.x); s[1] = f2bf(a.y); s[2] = f2bf(a.z); s[3] = f2bf(a.w);
  s[4] = f2bf(c.x); s[5] = f2bf(c.y); s[6] = f2bf(c.z); s[7] = f2bf(c.w);
  *(short8*)(Xb + i) = s;
}

// ------------- aggregation (bf16, START-semantics offs), 8-deep unroll ------
__global__ void k_gather_bf(const unsigned int* __restrict__ X1,
                            const int* __restrict__ deg, const int* __restrict__ offs,
                            const int* __restrict__ srt, unsigned int* __restrict__ h0) {
  int node = blockIdx.x * 4 + (threadIdx.x >> 6);
  int lane = threadIdx.x & 63;
  unsigned u = X1[(size_t)node * 64 + lane];
  float hx = bflo(u), hy = bfhi(u);
  int e = offs[node];
  int end = e + deg[node];
  for (; e + 8 <= end; e += 8) {
    int s0 = srt[e],     s1 = srt[e + 1], s2 = srt[e + 2], s3 = srt[e + 3];
    int s4 = srt[e + 4], s5 = srt[e + 5], s6 = srt[e + 6], s7 = srt[e + 7];
    unsigned u0 = X1[(size_t)s0 * 64 + lane];
    unsigned u1 = X1[(size_t)s1 * 64 + lane];
    unsigned u2 = X1[(size_t)s2 * 64 + lane];
    unsigned u3 = X1[(size_t)s3 * 64 + lane];
    unsigned u4 = X1[(size_t)s4 * 64 + lane];
    unsigned u5 = X1[(size_t)s5 * 64 + lane];
    unsigned u6 = X1[(size_t)s6 * 64 + lane];
    unsigned u7 = X1[(size_t)s7 * 64 + lane];
    hx += bflo(u0); hy += bfhi(u0);
    hx += bflo(u1); hy += bfhi(u1);
    hx += bflo(u2); hy += bfhi(u2);
    hx += bflo(u3); hy += bfhi(u3);
    hx += bflo(u4); hy += bfhi(u4);
    hx += bflo(u5); hy += bfhi(u5);
    hx += bflo(u6); hy += bfhi(u6);
    hx += bflo(u7); hy += bfhi(u7);
  }
  for (; e + 2 <= end; e += 2) {
    unsigned u0 = X1[(size_t)srt[e] * 64 + lane];
    unsigned u1 = X1[(size_t)srt[e + 1] * 64 + lane];
    hx += bflo(u0); hy += bfhi(u0);
    hx += bflo(u1); hy += bfhi(u1);
  }
  for (; e < end; ++e) {
    unsigned u0 = X1[(size_t)srt[e] * 64 + lane];
    hx += bflo(u0); hy += bfhi(u0);
  }
  h0[(size_t)node * 64 + lane] = ((unsigned)f2bf(hy) << 16) | f2bf(hx);
}

// ============ k_mlp3: barrier-free MLP, wave owns 16 rows ===================
// A from global bf16 h0; B-frags from global frag-major Wf (coalesced 1KB
// runs, L2-resident); h1 transpose through a private 4.4KB LDS stripe.
// 256 threads (4 waves), 4 blocks/CU, zero __syncthreads.
__launch_bounds__(256, 4)
__global__ void k_mlp3(const unsigned short* __restrict__ h0,
                       const unsigned short* __restrict__ Wf,
                       const float* __restrict__ b1v, const float* __restrict__ b2v,
                       float* __restrict__ out) {
  __shared__ __attribute__((aligned(16))) unsigned short lH[4][16 * PADK];

  const int t = threadIdx.x;
  const int wave = t >> 6, lane = t & 63;
  const int lr = lane & 15, lg = lane >> 4;
  const int wrow = blockIdx.x * 64 + wave * 16;

  // A fragments from global bf16 h0
  bf16x8 a[4];
#pragma unroll
  for (int kb = 0; kb < 4; ++kb) {
    int r = wrow + lr;
    if (r >= N_NODES) r = N_NODES - 1;          // clamp; result unused
    a[kb] = __builtin_bit_cast(bf16x8,
        *(const short8*)(h0 + (size_t)r * D + kb * 32 + lg * 8));
  }

  f32x4 acc[8];
#pragma unroll
  for (int nc = 0; nc < 8; ++nc) {
    float bb = b1v[nc * 16 + lr];
    acc[nc] = (f32x4){bb, bb, bb, bb};
  }

  // GEMM1: B-frags straight from global Wf (contiguous per wave)
#pragma unroll
  for (int nc = 0; nc < 8; ++nc) {
#pragma unroll
    for (int kb = 0; kb < 4; ++kb) {
      bf16x8 b = *(const bf16x8*)&Wf[(((nc * 4 + kb) * 64) + lane) * 8];
      acc[nc] = __builtin_amdgcn_mfma_f32_16x16x32_bf16(a[kb], b, acc[nc], 0, 0, 0);
    }
  }

  // ReLU -> h1 into own wave's LDS stripe (intra-wave dependency only)
#pragma unroll
  for (int nc = 0; nc < 8; ++nc) {
#pragma unroll
    for (int r = 0; r < 4; ++r) {
      float v = acc[nc][r];
      v = v > 0.f ? v : 0.f;
      lH[wave][(lg * 4 + r) * PADK + nc * 16 + lr] = f2bf(v);
    }
  }

  // A2 from own stripe
  bf16x8 a2[4];
#pragma unroll
  for (int kb = 0; kb < 4; ++kb)
    a2[kb] = *(const bf16x8*)&lH[wave][lr * PADK + kb * 32 + lg * 8];

#pragma unroll
  for (int nc = 0; nc < 8; ++nc) {
    float bb = b2v[nc * 16 + lr];
    acc[nc] = (f32x4){bb, bb, bb, bb};
  }

  // GEMM2
  const unsigned short* Wf2 = Wf + 16384;
#pragma unroll
  for (int nc = 0; nc < 8; ++nc) {
#pragma unroll
    for (int kb = 0; kb < 4; ++kb) {
      bf16x8 b = *(const bf16x8*)&Wf2[(((nc * 4 + kb) * 64) + lane) * 8];
      acc[nc] = __builtin_amdgcn_mfma_f32_16x16x32_bf16(a2[kb], b, acc[nc], 0, 0, 0);
    }
  }

  // store f32
#pragma unroll
  for (int nc = 0; nc < 8; ++nc) {
#pragma unroll
    for (int r = 0; r < 4; ++r) {
      int row = wrow + lg * 4 + r;
      if (row < N_NODES) out[(size_t)row * D + nc * 16 + lr] = acc[nc][r];
    }
  }
}

// ================= old CSR build (fallback path, end-semantics offs) ========

__global__ void k_hist(const int* __restrict__ dst, int* __restrict__ deg) {
  int i = blockIdx.x * 256 + threadIdx.x;
  if (i < N_EDGES) atomicAdd(&deg[dst[i]], 1);
}

__global__ void k_scan1(const int* __restrict__ deg, int* __restrict__ offs,
                        int* __restrict__ bsum) {
  __shared__ int s[1024];
  int t = threadIdx.x;
  int i = blockIdx.x * 1024 + t;
  int v = (i < N_NODES) ? deg[i] : 0;
  s[t] = v;
  __syncthreads();
  for (int d = 1; d < 1024; d <<= 1) {
    int x = (t >= d) ? s[t - d] : 0;
    __syncthreads();
    s[t] += x;
    __syncthreads();
  }
  if (i < N_NODES) offs[i] = s[t] - v;
  if (t == 1023) bsum[blockIdx.x] = s[t];
}

__global__ void k_scan2(int* __restrict__ bsum) {
  __shared__ int s[128];
  int t = threadIdx.x;
  int v = (t < 98) ? bsum[t] : 0;
  s[t] = v;
  __syncthreads();
  for (int d = 1; d < 128; d <<= 1) {
    int x = (t >= d) ? s[t - d] : 0;
    __syncthreads();
    s[t] += x;
    __syncthreads();
  }
  if (t < 98) bsum[t] = s[t] - v;
}

__global__ void k_scan3(int* __restrict__ offs, const int* __restrict__ bsum) {
  int i = blockIdx.x * 1024 + threadIdx.x;
  if (i < N_NODES) offs[i] += bsum[blockIdx.x];
}

__global__ void k_bucket(const int* __restrict__ src, const int* __restrict__ dst,
                         int* __restrict__ offs, int* __restrict__ srt) {
  int i = blockIdx.x * 256 + threadIdx.x;
  if (i < N_EDGES) {
    int pos = atomicAdd(&offs[dst[i]], 1);
    srt[pos] = src[i];
  }
}

// ------------- f32 fallback gather (END-semantics offs) -------------
__global__ void k_gather(const float* __restrict__ X, const int* __restrict__ deg,
                         const int* __restrict__ offs, const int* __restrict__ srt,
                         float* __restrict__ out) {
  int node = blockIdx.x * 4 + (threadIdx.x >> 6);
  int lane = threadIdx.x & 63;
  const float2* X2 = (const float2*)X;
  float2 h = X2[(size_t)node * 64 + lane];
  int end = offs[node];
  int dg = deg[node];
  for (int e = end - dg; e < end; ++e) {
    int s = srt[e];
    float2 x = X2[(size_t)s * 64 + lane];
    h.x += x.x; h.y += x.y;
  }
  ((float2*)out)[(size_t)node * 64 + lane] = h;
}

// ------------- fallback fused MLP (f32 h0 in d_out, in-place) -------------
#define BR 256

__launch_bounds__(512, 1)
__global__ void k_mlp(const float* __restrict__ h0,
                      const float* __restrict__ W1, const float* __restrict__ b1,
                      const float* __restrict__ W2, const float* __restrict__ b2,
                      float* __restrict__ out) {
  __shared__ __attribute__((aligned(16))) unsigned short lW[2 * 128 * PADK];
  __shared__ __attribute__((aligned(16))) unsigned short lH[BR * PADK];

  const int t = threadIdx.x;
  const int wave = t >> 6, lane = t & 63;
  const int lr = lane & 15, lg = lane >> 4;
  const int row0 = blockIdx.x * BR;
  const int wrow = row0 + wave * 32;

  for (int i = t; i < 128 * 128; i += 512) {
    int k = i >> 7, n = i & 127;
    lW[n * PADK + k] = f2bf(W1[i]);
    lW[128 * PADK + n * PADK + k] = f2bf(W2[i]);
  }

  bf16x8 a[2][4];
#pragma unroll
  for (int tr = 0; tr < 2; ++tr) {
#pragma unroll
    for (int kb = 0; kb < 4; ++kb) {
      int r = wrow + tr * 16 + lr;
      if (r >= N_NODES) r = N_NODES - 1;
      const float4* p = (const float4*)(h0 + (size_t)r * D + kb * 32 + lg * 8);
      float4 f0 = p[0], f1 = p[1];
      short8 s;
      s[0] = f2bf(f0.x); s[1] = f2bf(f0.y); s[2] = f2bf(f0.z); s[3] = f2bf(f0.w);
      s[4] = f2bf(f1.x); s[5] = f2bf(f1.y); s[6] = f2bf(f1.z); s[7] = f2bf(f1.w);
      a[tr][kb] = __builtin_bit_cast(bf16x8, s);
    }
  }

  f32x4 acc[2][8];
#pragma unroll
  for (int nc = 0; nc < 8; ++nc) {
    float bb = b1[nc * 16 + lr];
#pragma unroll
    for (int tr = 0; tr < 2; ++tr) acc[tr][nc] = (f32x4){bb, bb, bb, bb};
  }

  __syncthreads();

#pragma unroll
  for (int nc = 0; nc < 8; ++nc) {
#pragma unroll
    for (int kb = 0; kb < 4; ++kb) {
      bf16x8 b = *(const bf16x8*)&lW[(nc * 16 + lr) * PADK + kb * 32 + lg * 8];
#pragma unroll
      for (int tr = 0; tr < 2; ++tr)
        acc[tr][nc] = __builtin_amdgcn_mfma_f32_16x16x32_bf16(a[tr][kb], b, acc[tr][nc], 0, 0, 0);
    }
  }

#pragma unroll
  for (int tr = 0; tr < 2; ++tr) {
#pragma unroll
    for (int nc = 0; nc < 8; ++nc) {
#pragma unroll
      for (int r = 0; r < 4; ++r) {
        float v = acc[tr][nc][r];
        v = v > 0.f ? v : 0.f;
        int lrow = wave * 32 + tr * 16 + lg * 4 + r;
        lH[lrow * PADK + nc * 16 + lr] = f2bf(v);
      }
    }
  }

  __syncthreads();

  bf16x8 a2[2][4];
#pragma unroll
  for (int tr = 0; tr < 2; ++tr) {
#pragma unroll
    for (int kb = 0; kb < 4; ++kb)
      a2[tr][kb] = *(const bf16x8*)&lH[(wave * 32 + tr * 16 + lr) * PADK + kb * 32 + lg * 8];
  }

#pragma unroll
  for (int nc = 0; nc < 8; ++nc) {
    float bb = b2[nc * 16 + lr];
#pragma unroll
    for (int tr = 0; tr < 2; ++tr) acc[tr][nc] = (f32x4){bb, bb, bb, bb};
  }

#pragma unroll
  for (int nc = 0; nc < 8; ++nc) {
#pragma unroll
    for (int kb = 0; kb < 4; ++kb) {
      bf16x8 b = *(const bf16x8*)&lW[128 * PADK + (nc * 16 + lr) * PADK + kb * 32 + lg * 8];
#pragma unroll
      for (int tr = 0; tr < 2; ++tr)
        acc[tr][nc] = __builtin_amdgcn_mfma_f32_16x16x32_bf16(a2[tr][kb], b, acc[tr][nc], 0, 0, 0);
    }
  }

#pragma unroll
  for (int tr = 0; tr < 2; ++tr) {
#pragma unroll
    for (int nc = 0; nc < 8; ++nc) {
#pragma unroll
      for (int r = 0; r < 4; ++r) {
        int row = wrow + tr * 16 + lg * 4 + r;
        if (row < N_NODES) out[(size_t)row * D + nc * 16 + lr] = acc[tr][nc][r];
      }
    }
  }
}

extern "C" void kernel_launch(void* const* d_in, const int* in_sizes, int n_in,
                              void* d_out, int out_size, void* d_ws, size_t ws_size,
                              hipStream_t stream) {
  const float* X  = (const float*)d_in[0];
  const float* W1 = (const float*)d_in[1];
  const float* b1 = (const float*)d_in[2];
  const float* W2 = (const float*)d_in[3];
  const float* b2 = (const float*)d_in[4];
  const int* esrc = (const int*)d_in[5];
  const int* edst = (const int*)d_in[6];
  float* out = (float*)d_out;

  char* ws = (char*)d_ws;
  int* deg      = (int*)(ws);                    // 400,000 B
  int* offs     = (int*)(ws + 400000);           // 400,000 B
  int* g_bincnt = (int*)(ws + 800000);           // 1 KB (also bsum in fallback)
  int* srt      = (int*)(ws + 802048);           // 6.4 MB -> 7,202,048
  unsigned short* Xb  = (unsigned short*)(ws + 7202048);   // 25.6 MB -> 32,802,048
  unsigned short* h0b = (unsigned short*)(ws + 32802048);  // 25.6 MB -> 58,402,048
  unsigned* binbuf = (unsigned*)(ws + 32802048); // 7.84 MB, aliases h0b (dead by gather)
  unsigned short* Wf = (unsigned short*)(ws + 58402048);   // 65,536 B frag-major W1|W2
  const size_t NEED = 58471680;

  if (ws_size >= NEED) {
    hipMemsetAsync(g_bincnt, 0, NBINS * sizeof(int), stream);
    k_bin<<<(N_EDGES + EPB - 1) / EPB, 512, 0, stream>>>(esrc, edst, g_bincnt, binbuf);
    k_mid<<<MID_SORT_BLOCKS + MID_W_BLOCKS + MID_CVT_BLOCKS, 512, 0, stream>>>(
        binbuf, g_bincnt, srt, deg, offs, X, Xb, W1, W2, Wf);
    k_gather_bf<<<N_NODES / 4, 256, 0, stream>>>((const unsigned*)Xb, deg, offs, srt,
                                                 (unsigned*)h0b);
    k_mlp3<<<(N_NODES + 63) / 64, 256, 0, stream>>>(h0b, Wf, b1, b2, out);
  } else {
    // fallback: proven round-1 pipeline (f32 gather, END-semantics offs)
    int* bsum = g_bincnt;
    hipMemsetAsync(deg, 0, N_NODES * sizeof(int), stream);
    k_hist  <<<N_EDGES / 256, 256, 0, stream>>>(edst, deg);
    k_scan1 <<<98, 1024, 0, stream>>>(deg, offs, bsum);
    k_scan2 <<<1, 128, 0, stream>>>(bsum);
    k_scan3 <<<98, 1024, 0, stream>>>(offs, bsum);
    k_bucket<<<N_EDGES / 256, 256, 0, stream>>>(esrc, edst, offs, srt);
    k_gather<<<N_NODES / 4, 256, 0, stream>>>(X, deg, offs, srt, out);
    k_mlp   <<<(N_NODES + BR - 1) / BR, 512, 0, stream>>>(out, W1, b1, W2, b2, out);
  }
}

// Round 9
// 141.436 us; speedup vs baseline: 1.0014x; 1.0014x over previous
//
#include <hip/hip_runtime.h>
#include <hip/hip_bf16.h>

#define N_NODES 100000
#define N_EDGES 1600000
#define D 128

#define NBINS 196       // ceil(100000 / 512)
#define BINSHIFT 9      // 512 nodes per bin
#define BINCAP 10000    // avg 8163 edges/bin
#define EPB 2048        // edges per bin block: 782 blocks -> 4 blocks/CU (was 196 = 1/CU, latency-bound)

// k_mid block layout: [0,196) binsort, [196,204) W image, [204,3329) X cvt
#define MID_SORT_BLOCKS 196
#define MID_W_BLOCKS 8
#define MID_CVT_BLOCKS 3125    // 100000*128 / (512*8)

#define PADK 136

typedef __bf16 bf16x8 __attribute__((ext_vector_type(8)));
typedef short short8 __attribute__((ext_vector_type(8)));
typedef float f32x4 __attribute__((ext_vector_type(4)));

__device__ __forceinline__ unsigned short f2bf(float f) {
  union { float f; unsigned u; } c; c.f = f;
  unsigned u = c.u;
  u += 0x7FFFu + ((u >> 16) & 1u);   // round-to-nearest-even
  return (unsigned short)(u >> 16);
}
__device__ __forceinline__ float bflo(unsigned u) {
  union { unsigned u; float f; } c; c.u = u << 16; return c.f;
}
__device__ __forceinline__ float bfhi(unsigned u) {
  union { unsigned u; float f; } c; c.u = u & 0xFFFF0000u; return c.f;
}

// ============ k_bin: edge binning; packs (dst&511)<<17 | src ================
__launch_bounds__(512)
__global__ void k_bin(const int* __restrict__ esrc, const int* __restrict__ edst,
                      int* __restrict__ g_bincnt, unsigned* __restrict__ binbuf) {
  __shared__ int cnt[NBINS];
  __shared__ int base[NBINS];
  const int b = blockIdx.x, t = threadIdx.x;
  const int e0 = b * EPB;
  const int ne = min(EPB, N_EDGES - e0);
  for (int i = t; i < NBINS; i += 512) cnt[i] = 0;
  __syncthreads();
  for (int i = t; i < ne; i += 512)
    atomicAdd(&cnt[edst[e0 + i] >> BINSHIFT], 1);
  __syncthreads();
  for (int i = t; i < NBINS; i += 512) {
    base[i] = atomicAdd(&g_bincnt[i], cnt[i]);
    cnt[i] = 0;
  }
  __syncthreads();
  for (int i = t; i < ne; i += 512) {
    int d = edst[e0 + i];
    int s = esrc[e0 + i];
    int bi = d >> BINSHIFT;
    int pos = base[bi] + atomicAdd(&cnt[bi], 1);
    binbuf[(size_t)bi * BINCAP + pos] = ((unsigned)(d & 511) << 17) | (unsigned)s;
  }
}

// ============ k_mid: fused binsort + W image + X cvt ========================
__launch_bounds__(512)
__global__ void k_mid(const unsigned* __restrict__ binbuf, const int* __restrict__ g_bincnt,
                      int* __restrict__ srt, int* __restrict__ deg, int* __restrict__ offs,
                      const float* __restrict__ X, unsigned short* __restrict__ Xb,
                      const float* __restrict__ W1, const float* __restrict__ W2,
                      unsigned short* __restrict__ Wimg) {
  const int b = blockIdx.x, t = threadIdx.x;

  if (b < MID_SORT_BLOCKS) {
    // ---- per-bin counting sort; emits deg/offs (START semantics) ----
    __shared__ int hist[512];
    __shared__ int scan[512];
    __shared__ int sb[256];
    if (t < 256) sb[t] = (t < NBINS) ? g_bincnt[t] : 0;
    __syncthreads();
    for (int d = 1; d < 256; d <<= 1) {
      int x = 0;
      if (t < 256 && t >= d) x = sb[t - d];
      __syncthreads();
      if (t < 256) sb[t] += x;
      __syncthreads();
    }
    const int cntb = g_bincnt[b];
    const int gbase = (b == 0) ? 0 : sb[b - 1];
    const int n0 = b << BINSHIFT;
    const unsigned* ebuf = binbuf + (size_t)b * BINCAP;

    hist[t] = 0;
    __syncthreads();
    for (int i = t; i < cntb; i += 512)
      atomicAdd(&hist[ebuf[i] >> 17], 1);
    __syncthreads();
    int v = hist[t];
    scan[t] = v;
    __syncthreads();
    for (int d = 1; d < 512; d <<= 1) {
      int x = (t >= d) ? scan[t - d] : 0;
      __syncthreads();
      scan[t] += x;
      __syncthreads();
    }
    int n = n0 + t;
    if (n < N_NODES) {
      deg[n] = v;
      offs[n] = gbase + scan[t] - v;   // segment start
    }
    hist[t] = scan[t] - v;             // bin-local write cursor
    __syncthreads();
    for (int i = t; i < cntb; i += 512) {
      unsigned e = ebuf[i];
      int pos = atomicAdd(&hist[e >> 17], 1);
      srt[gbase + pos] = (int)(e & 0x1FFFFu);
    }
    return;
  }
  if (b < MID_SORT_BLOCKS + MID_W_BLOCKS) {
    int bb = b - MID_SORT_BLOCKS;
    const float* W = (bb & 4) ? W2 : W1;
    unsigned short* img = Wimg + ((bb & 4) ? 128 * PADK : 0);
    int k0 = (bb & 3) * 32;
#pragma unroll
    for (int it = 0; it < 8; ++it) {
      int idx = it * 512 + t;                 // 4096 entries: 32 k x 128 n
      int k = k0 + (idx >> 7), n = idx & 127;
      img[n * PADK + k] = f2bf(W[k * 128 + n]);
    }
    return;
  }
  // ---- X f32 -> bf16 ----
  size_t i = ((size_t)(b - MID_SORT_BLOCKS - MID_W_BLOCKS) * 512 + t) * 8;
  const float4* p = (const float4*)(X + i);
  float4 a = p[0], c = p[1];
  short8 s;
  s[0] = f2bf(a.x); s[1] = f2bf(a.y); s[2] = f2bf(a.z); s[3] = f2bf(a.w);
  s[4] = f2bf(c.x); s[5] = f2bf(c.y); s[6] = f2bf(c.z); s[7] = f2bf(c.w);
  *(short8*)(Xb + i) = s;
}

// ------------- aggregation (bf16, START-semantics offs), 8-deep unroll ------
__global__ void k_gather_bf(const unsigned int* __restrict__ X1,
                            const int* __restrict__ deg, const int* __restrict__ offs,
                            const int* __restrict__ srt, unsigned int* __restrict__ h0) {
  int node = blockIdx.x * 4 + (threadIdx.x >> 6);
  int lane = threadIdx.x & 63;
  unsigned u = X1[(size_t)node * 64 + lane];
  float hx = bflo(u), hy = bfhi(u);
  int e = offs[node];
  int end = e + deg[node];
  for (; e + 8 <= end; e += 8) {
    int s0 = srt[e],     s1 = srt[e + 1], s2 = srt[e + 2], s3 = srt[e + 3];
    int s4 = srt[e + 4], s5 = srt[e + 5], s6 = srt[e + 6], s7 = srt[e + 7];
    unsigned u0 = X1[(size_t)s0 * 64 + lane];
    unsigned u1 = X1[(size_t)s1 * 64 + lane];
    unsigned u2 = X1[(size_t)s2 * 64 + lane];
    unsigned u3 = X1[(size_t)s3 * 64 + lane];
    unsigned u4 = X1[(size_t)s4 * 64 + lane];
    unsigned u5 = X1[(size_t)s5 * 64 + lane];
    unsigned u6 = X1[(size_t)s6 * 64 + lane];
    unsigned u7 = X1[(size_t)s7 * 64 + lane];
    hx += bflo(u0); hy += bfhi(u0);
    hx += bflo(u1); hy += bfhi(u1);
    hx += bflo(u2); hy += bfhi(u2);
    hx += bflo(u3); hy += bfhi(u3);
    hx += bflo(u4); hy += bfhi(u4);
    hx += bflo(u5); hy += bfhi(u5);
    hx += bflo(u6); hy += bfhi(u6);
    hx += bflo(u7); hy += bfhi(u7);
  }
  for (; e + 2 <= end; e += 2) {
    unsigned u0 = X1[(size_t)srt[e] * 64 + lane];
    unsigned u1 = X1[(size_t)srt[e + 1] * 64 + lane];
    hx += bflo(u0); hy += bfhi(u0);
    hx += bflo(u1); hy += bfhi(u1);
  }
  for (; e < end; ++e) {
    unsigned u0 = X1[(size_t)srt[e] * 64 + lane];
    hx += bflo(u0); hy += bfhi(u0);
  }
  h0[(size_t)node * 64 + lane] = ((unsigned)f2bf(hy) << 16) | f2bf(hx);
}

// ============ k_mlp2: BR=128, 8 waves (wave owns 16 rows), 2 blocks/CU ======
// W1 staged in LDS; W2 prefetched into REGISTERS before barrier 1 so the
// restage after GEMM1 is pure ds_write (no global latency in the gap).
#define BR2 128

__launch_bounds__(512, 4)
__global__ void k_mlp2(const unsigned short* __restrict__ h0,
                       const unsigned short* __restrict__ Wimg,
                       const float* __restrict__ b1v, const float* __restrict__ b2v,
                       float* __restrict__ out) {
  __shared__ __attribute__((aligned(16))) unsigned short lW[128 * PADK];
  __shared__ __attribute__((aligned(16))) unsigned short lH[BR2 * PADK];

  const int t = threadIdx.x;
  const int wave = t >> 6, lane = t & 63;
  const int lr = lane & 15, lg = lane >> 4;
  const int row0 = blockIdx.x * BR2;
  const int wrow = row0 + wave * 16;

  const uint4* wi = (const uint4*)Wimg;
  uint4* lw = (uint4*)lW;

  // stage W1 image (2176 uint4)
  for (int i = t; i < 2176; i += 512) lw[i] = wi[i];

  // prefetch W2 image into registers (2176 = 4*512 + 128)
  uint4 w2r0 = wi[2176 + t];
  uint4 w2r1 = wi[2176 + 512 + t];
  uint4 w2r2 = wi[2176 + 1024 + t];
  uint4 w2r3 = wi[2176 + 1536 + t];
  uint4 w2r4 = {};
  if (t < 128) w2r4 = wi[2176 + 2048 + t];

  // A fragments from global bf16 h0
  bf16x8 a[4];
#pragma unroll
  for (int kb = 0; kb < 4; ++kb) {
    int r = wrow + lr;
    if (r >= N_NODES) r = N_NODES - 1;          // clamp; result unused
    a[kb] = __builtin_bit_cast(bf16x8,
        *(const short8*)(h0 + (size_t)r * D + kb * 32 + lg * 8));
  }

  f32x4 acc[8];
#pragma unroll
  for (int nc = 0; nc < 8; ++nc) {
    float bb = b1v[nc * 16 + lr];
    acc[nc] = (f32x4){bb, bb, bb, bb};
  }

  __syncthreads();   // W1 staged

  // GEMM1
#pragma unroll
  for (int nc = 0; nc < 8; ++nc) {
#pragma unroll
    for (int kb = 0; kb < 4; ++kb) {
      bf16x8 b = *(const bf16x8*)&lW[(nc * 16 + lr) * PADK + kb * 32 + lg * 8];
      acc[nc] = __builtin_amdgcn_mfma_f32_16x16x32_bf16(a[kb], b, acc[nc], 0, 0, 0);
    }
  }

  __syncthreads();   // everyone done reading W1

  // restage W2 from registers (pure LDS writes)
  lw[t] = w2r0;
  lw[512 + t] = w2r1;
  lw[1024 + t] = w2r2;
  lw[1536 + t] = w2r3;
  if (t < 128) lw[2048 + t] = w2r4;

  // ReLU -> h1 into own stripe (intra-wave dependency only)
#pragma unroll
  for (int nc = 0; nc < 8; ++nc) {
#pragma unroll
    for (int r = 0; r < 4; ++r) {
      float v = acc[nc][r];
      v = v > 0.f ? v : 0.f;
      lH[(wave * 16 + lg * 4 + r) * PADK + nc * 16 + lr] = f2bf(v);
    }
  }

  __syncthreads();   // W2 staged

  bf16x8 a2[4];
#pragma unroll
  for (int kb = 0; kb < 4; ++kb)
    a2[kb] = *(const bf16x8*)&lH[(wave * 16 + lr) * PADK + kb * 32 + lg * 8];

#pragma unroll
  for (int nc = 0; nc < 8; ++nc) {
    float bb = b2v[nc * 16 + lr];
    acc[nc] = (f32x4){bb, bb, bb, bb};
  }

  // GEMM2
#pragma unroll
  for (int nc = 0; nc < 8; ++nc) {
#pragma unroll
    for (int kb = 0; kb < 4; ++kb) {
      bf16x8 b = *(const bf16x8*)&lW[(nc * 16 + lr) * PADK + kb * 32 + lg * 8];
      acc[nc] = __builtin_amdgcn_mfma_f32_16x16x32_bf16(a2[kb], b, acc[nc], 0, 0, 0);
    }
  }

  // store f32
#pragma unroll
  for (int nc = 0; nc < 8; ++nc) {
#pragma unroll
    for (int r = 0; r < 4; ++r) {
      int row = wrow + lg * 4 + r;
      if (row < N_NODES) out[(size_t)row * D + nc * 16 + lr] = acc[nc][r];
    }
  }
}

// ================= old CSR build (fallback path, end-semantics offs) ========

__global__ void k_hist(const int* __restrict__ dst, int* __restrict__ deg) {
  int i = blockIdx.x * 256 + threadIdx.x;
  if (i < N_EDGES) atomicAdd(&deg[dst[i]], 1);
}

__global__ void k_scan1(const int* __restrict__ deg, int* __restrict__ offs,
                        int* __restrict__ bsum) {
  __shared__ int s[1024];
  int t = threadIdx.x;
  int i = blockIdx.x * 1024 + t;
  int v = (i < N_NODES) ? deg[i] : 0;
  s[t] = v;
  __syncthreads();
  for (int d = 1; d < 1024; d <<= 1) {
    int x = (t >= d) ? s[t - d] : 0;
    __syncthreads();
    s[t] += x;
    __syncthreads();
  }
  if (i < N_NODES) offs[i] = s[t] - v;
  if (t == 1023) bsum[blockIdx.x] = s[t];
}

__global__ void k_scan2(int* __restrict__ bsum) {
  __shared__ int s[128];
  int t = threadIdx.x;
  int v = (t < 98) ? bsum[t] : 0;
  s[t] = v;
  __syncthreads();
  for (int d = 1; d < 128; d <<= 1) {
    int x = (t >= d) ? s[t - d] : 0;
    __syncthreads();
    s[t] += x;
    __syncthreads();
  }
  if (t < 98) bsum[t] = s[t] - v;
}

__global__ void k_scan3(int* __restrict__ offs, const int* __restrict__ bsum) {
  int i = blockIdx.x * 1024 + threadIdx.x;
  if (i < N_NODES) offs[i] += bsum[blockIdx.x];
}

__global__ void k_bucket(const int* __restrict__ src, const int* __restrict__ dst,
                         int* __restrict__ offs, int* __restrict__ srt) {
  int i = blockIdx.x * 256 + threadIdx.x;
  if (i < N_EDGES) {
    int pos = atomicAdd(&offs[dst[i]], 1);
    srt[pos] = src[i];
  }
}

// ------------- f32 fallback gather (END-semantics offs) -------------
__global__ void k_gather(const float* __restrict__ X, const int* __restrict__ deg,
                         const int* __restrict__ offs, const int* __restrict__ srt,
                         float* __restrict__ out) {
  int node = blockIdx.x * 4 + (threadIdx.x >> 6);
  int lane = threadIdx.x & 63;
  const float2* X2 = (const float2*)X;
  float2 h = X2[(size_t)node * 64 + lane];
  int end = offs[node];
  int dg = deg[node];
  for (int e = end - dg; e < end; ++e) {
    int s = srt[e];
    float2 x = X2[(size_t)s * 64 + lane];
    h.x += x.x; h.y += x.y;
  }
  ((float2*)out)[(size_t)node * 64 + lane] = h;
}

// ------------- fallback fused MLP (f32 h0 in d_out, in-place) -------------
#define BR 256

__launch_bounds__(512, 1)
__global__ void k_mlp(const float* __restrict__ h0,
                      const float* __restrict__ W1, const float* __restrict__ b1,
                      const float* __restrict__ W2, const float* __restrict__ b2,
                      float* __restrict__ out) {
  __shared__ __attribute__((aligned(16))) unsigned short lW[2 * 128 * PADK];
  __shared__ __attribute__((aligned(16))) unsigned short lH[BR * PADK];

  const int t = threadIdx.x;
  const int wave = t >> 6, lane = t & 63;
  const int lr = lane & 15, lg = lane >> 4;
  const int row0 = blockIdx.x * BR;
  const int wrow = row0 + wave * 32;

  for (int i = t; i < 128 * 128; i += 512) {
    int k = i >> 7, n = i & 127;
    lW[n * PADK + k] = f2bf(W1[i]);
    lW[128 * PADK + n * PADK + k] = f2bf(W2[i]);
  }

  bf16x8 a[2][4];
#pragma unroll
  for (int tr = 0; tr < 2; ++tr) {
#pragma unroll
    for (int kb = 0; kb < 4; ++kb) {
      int r = wrow + tr * 16 + lr;
      if (r >= N_NODES) r = N_NODES - 1;
      const float4* p = (const float4*)(h0 + (size_t)r * D + kb * 32 + lg * 8);
      float4 f0 = p[0], f1 = p[1];
      short8 s;
      s[0] = f2bf(f0.x); s[1] = f2bf(f0.y); s[2] = f2bf(f0.z); s[3] = f2bf(f0.w);
      s[4] = f2bf(f1.x); s[5] = f2bf(f1.y); s[6] = f2bf(f1.z); s[7] = f2bf(f1.w);
      a[tr][kb] = __builtin_bit_cast(bf16x8, s);
    }
  }

  f32x4 acc[2][8];
#pragma unroll
  for (int nc = 0; nc < 8; ++nc) {
    float bb = b1[nc * 16 + lr];
#pragma unroll
    for (int tr = 0; tr < 2; ++tr) acc[tr][nc] = (f32x4){bb, bb, bb, bb};
  }

  __syncthreads();

#pragma unroll
  for (int nc = 0; nc < 8; ++nc) {
#pragma unroll
    for (int kb = 0; kb < 4; ++kb) {
      bf16x8 b = *(const bf16x8*)&lW[(nc * 16 + lr) * PADK + kb * 32 + lg * 8];
#pragma unroll
      for (int tr = 0; tr < 2; ++tr)
        acc[tr][nc] = __builtin_amdgcn_mfma_f32_16x16x32_bf16(a[tr][kb], b, acc[tr][nc], 0, 0, 0);
    }
  }

#pragma unroll
  for (int tr = 0; tr < 2; ++tr) {
#pragma unroll
    for (int nc = 0; nc < 8; ++nc) {
#pragma unroll
      for (int r = 0; r < 4; ++r) {
        float v = acc[tr][nc][r];
        v = v > 0.f ? v : 0.f;
        int lrow = wave * 32 + tr * 16 + lg * 4 + r;
        lH[lrow * PADK + nc * 16 + lr] = f2bf(v);
      }
    }
  }

  __syncthreads();

  bf16x8 a2[2][4];
#pragma unroll
  for (int tr = 0; tr < 2; ++tr) {
#pragma unroll
    for (int kb = 0; kb < 4; ++kb)
      a2[tr][kb] = *(const bf16x8*)&lH[(wave * 32 + tr * 16 + lr) * PADK + kb * 32 + lg * 8];
  }

#pragma unroll
  for (int nc = 0; nc < 8; ++nc) {
    float bb = b2[nc * 16 + lr];
#pragma unroll
    for (int tr = 0; tr < 2; ++tr) acc[tr][nc] = (f32x4){bb, bb, bb, bb};
  }

#pragma unroll
  for (int nc = 0; nc < 8; ++nc) {
#pragma unroll
    for (int kb = 0; kb < 4; ++kb) {
      bf16x8 b = *(const bf16x8*)&lW[128 * PADK + (nc * 16 + lr) * PADK + kb * 32 + lg * 8];
#pragma unroll
      for (int tr = 0; tr < 2; ++tr)
        acc[tr][nc] = __builtin_amdgcn_mfma_f32_16x16x32_bf16(a2[tr][kb], b, acc[tr][nc], 0, 0, 0);
    }
  }

#pragma unroll
  for (int tr = 0; tr < 2; ++tr) {
#pragma unroll
    for (int nc = 0; nc < 8; ++nc) {
#pragma unroll
      for (int r = 0; r < 4; ++r) {
        int row = wrow + tr * 16 + lg * 4 + r;
        if (row < N_NODES) out[(size_t)row * D + nc * 16 + lr] = acc[tr][nc][r];
      }
    }
  }
}

extern "C" void kernel_launch(void* const* d_in, const int* in_sizes, int n_in,
                              void* d_out, int out_size, void* d_ws, size_t ws_size,
                              hipStream_t stream) {
  const float* X  = (const float*)d_in[0];
  const float* W1 = (const float*)d_in[1];
  const float* b1 = (const float*)d_in[2];
  const float* W2 = (const float*)d_in[3];
  const float* b2 = (const float*)d_in[4];
  const int* esrc = (const int*)d_in[5];
  const int* edst = (const int*)d_in[6];
  float* out = (float*)d_out;

  char* ws = (char*)d_ws;
  int* deg      = (int*)(ws);                    // 400,000 B
  int* offs     = (int*)(ws + 400000);           // 400,000 B
  int* g_bincnt = (int*)(ws + 800000);           // 1 KB (also bsum in fallback)
  int* srt      = (int*)(ws + 802048);           // 6.4 MB -> 7,202,048
  unsigned short* Xb  = (unsigned short*)(ws + 7202048);   // 25.6 MB -> 32,802,048
  unsigned short* h0b = (unsigned short*)(ws + 32802048);  // 25.6 MB -> 58,402,048
  unsigned* binbuf = (unsigned*)(ws + 32802048); // 7.84 MB, aliases h0b (dead by gather)
  unsigned short* Wimg = (unsigned short*)(ws + 58402048); // 69,632 B padded bf16 W image
  const size_t NEED = 58471680;

  if (ws_size >= NEED) {
    hipMemsetAsync(g_bincnt, 0, NBINS * sizeof(int), stream);
    k_bin<<<(N_EDGES + EPB - 1) / EPB, 512, 0, stream>>>(esrc, edst, g_bincnt, binbuf);
    k_mid<<<MID_SORT_BLOCKS + MID_W_BLOCKS + MID_CVT_BLOCKS, 512, 0, stream>>>(
        binbuf, g_bincnt, srt, deg, offs, X, Xb, W1, W2, Wimg);
    k_gather_bf<<<N_NODES / 4, 256, 0, stream>>>((const unsigned*)Xb, deg, offs, srt,
                                                 (unsigned*)h0b);
    k_mlp2<<<(N_NODES + BR2 - 1) / BR2, 512, 0, stream>>>(h0b, Wimg, b1, b2, out);
  } else {
    // fallback: proven round-1 pipeline (f32 gather, END-semantics offs)
    int* bsum = g_bincnt;
    hipMemsetAsync(deg, 0, N_NODES * sizeof(int), stream);
    k_hist  <<<N_EDGES / 256, 256, 0, stream>>>(edst, deg);
    k_scan1 <<<98, 1024, 0, stream>>>(deg, offs, bsum);
    k_scan2 <<<1, 128, 0, stream>>>(bsum);
    k_scan3 <<<98, 1024, 0, stream>>>(offs, bsum);
    k_bucket<<<N_EDGES / 256, 256, 0, stream>>>(esrc, edst, offs, srt);
    k_gather<<<N_NODES / 4, 256, 0, stream>>>(X, deg, offs, srt, out);
    k_mlp   <<<(N_NODES + BR - 1) / BR, 512, 0, stream>>>(out, W1, b1, W2, b2, out);
  }
}

// Round 10
// 132.317 us; speedup vs baseline: 1.0704x; 1.0689x over previous
//
#include <hip/hip_runtime.h>
#include <hip/hip_bf16.h>

#define N_NODES 100000
#define N_EDGES 1600000
#define D 128

#define NBINS 196       // ceil(100000 / 512) node bins
#define BINSHIFT 9      // 512 nodes per bin
#define EPB 8192        // edges per region (k_bin2 block)
#define RBLK 196        // edge regions = ceil(N_EDGES / EPB)
#define EBUF_CAP 8960   // LDS staging cap per bin (mean 8192, sigma ~90)

// k_mid block layout: [0,196) binsort, [196,204) W image, [204,3329) X cvt
#define MID_SORT_BLOCKS 196
#define MID_W_BLOCKS 8
#define MID_CVT_BLOCKS 3125    // 100000*128 / (512*8)

#define PADK 136

typedef __bf16 bf16x8 __attribute__((ext_vector_type(8)));
typedef short short8 __attribute__((ext_vector_type(8)));
typedef float f32x4 __attribute__((ext_vector_type(4)));

__device__ __forceinline__ unsigned short f2bf(float f) {
  union { float f; unsigned u; } c; c.f = f;
  unsigned u = c.u;
  u += 0x7FFFu + ((u >> 16) & 1u);   // round-to-nearest-even
  return (unsigned short)(u >> 16);
}
__device__ __forceinline__ float bflo(unsigned u) {
  union { unsigned u; float f; } c; c.u = u << 16; return c.f;
}
__device__ __forceinline__ float bfhi(unsigned u) {
  union { unsigned u; float f; } c; c.u = u & 0xFFFF0000u; return c.f;
}

// ============ k_bin2: atomic-free edge binning via LDS counting sort ========
// Block b groups its 8192 edges by bin INSIDE LDS, then streams the 32KB out
// as dense uint4 stores into its private region binbuf[b*EPB..]. Also emits
// per-(bin,region) count/start matrices (transposed for coalesced reads).
__launch_bounds__(512)
__global__ void k_bin2(const int* __restrict__ esrc, const int* __restrict__ edst,
                       unsigned* __restrict__ binbuf, int* __restrict__ cntmatT,
                       int* __restrict__ startmatT) {
  __shared__ unsigned lbuf[EPB];       // 32 KB
  __shared__ int cnt[NBINS];
  __shared__ int base[NBINS];
  __shared__ int cur[NBINS];
  __shared__ int scanb[256];
  const int b = blockIdx.x, t = threadIdx.x;
  const int e0 = b * EPB;
  const int ne = min(EPB, N_EDGES - e0);

  for (int i = t; i < NBINS; i += 512) { cnt[i] = 0; cur[i] = 0; }
  __syncthreads();
  for (int i = t; i < ne; i += 512)
    atomicAdd(&cnt[edst[e0 + i] >> BINSHIFT], 1);
  __syncthreads();
  if (t < 256) scanb[t] = (t < NBINS) ? cnt[t] : 0;
  __syncthreads();
  for (int d = 1; d < 256; d <<= 1) {
    int x = 0;
    if (t < 256 && t >= d) x = scanb[t - d];
    __syncthreads();
    if (t < 256) scanb[t] += x;
    __syncthreads();
  }
  if (t < NBINS) base[t] = scanb[t] - cnt[t];
  __syncthreads();
  for (int i = t; i < ne; i += 512) {
    int d = edst[e0 + i];
    int s = esrc[e0 + i];
    int bi = d >> BINSHIFT;
    int pos = base[bi] + atomicAdd(&cur[bi], 1);
    lbuf[pos] = ((unsigned)(d & 511) << 17) | (unsigned)s;
  }
  __syncthreads();
  // dense stream-out (full 32KB; garbage tail never referenced via counts)
  uint4* dst4 = (uint4*)(binbuf + (size_t)b * EPB);
  const uint4* src4 = (const uint4*)lbuf;
  for (int i = t; i < EPB / 4; i += 512) dst4[i] = src4[i];
  if (t < NBINS) {
    cntmatT[t * RBLK + b] = cnt[t];     // [bin][region]
    startmatT[t * RBLK + b] = base[t];
  }
}

// ============ k_mid: fused binsort + W image + X cvt ========================
__launch_bounds__(512)
__global__ void k_mid(const unsigned* __restrict__ binbuf, const int* __restrict__ cntmatT,
                      const int* __restrict__ startmatT,
                      int* __restrict__ srt, int* __restrict__ deg, int* __restrict__ offs,
                      const float* __restrict__ X, unsigned short* __restrict__ Xb,
                      const float* __restrict__ W1, const float* __restrict__ W2,
                      unsigned short* __restrict__ Wimg) {
  const int b = blockIdx.x, t = threadIdx.x;

  if (b < MID_SORT_BLOCKS) {
    // ---- per-bin counting sort; emits deg/offs (START), dense srt ----
    __shared__ unsigned ebuf[EBUF_CAP];  // 35 KB
    __shared__ int hist[512];
    __shared__ int scn[512];
    __shared__ int rcnt[RBLK];
    __shared__ int roff[RBLK];
    __shared__ int eoff[RBLK];
    __shared__ int colsc[256];

    // this bin's per-region counts/starts (coalesced 784B rows)
    for (int r = t; r < RBLK; r += 512) {
      rcnt[r] = cntmatT[b * RBLK + r];
      roff[r] = startmatT[b * RBLK + r];
    }
    // column sums of cntmatT -> per-bin totals (thread t sums bin t's row)
    int cs = 0;
    if (t < NBINS) {
      const uint4* row = (const uint4*)(cntmatT + t * RBLK);
#pragma unroll 7
      for (int j = 0; j < RBLK / 4; ++j) {
        uint4 v = row[j];
        cs += (int)(v.x + v.y + v.z + v.w);
      }
    }
    if (t < 256) colsc[t] = (t < NBINS) ? cs : 0;
    __syncthreads();
    for (int d = 1; d < 256; d <<= 1) {
      int x = 0;
      if (t < 256 && t >= d) x = colsc[t - d];
      __syncthreads();
      if (t < 256) colsc[t] += x;
      __syncthreads();
    }
    const int total = cntmatT ? 0 : 0;  // placeholder, recomputed below
    (void)total;
    const int mytotal_holder = 0; (void)mytotal_holder;
    __syncthreads();
    const int mytotal = colsc[b] - ((b == 0) ? 0 : colsc[b - 1]);
    const int gbase = (b == 0) ? 0 : colsc[b - 1];

    // eoff: exclusive scan of rcnt over regions
    if (t < 256) scn[t] = (t < RBLK) ? rcnt[t] : 0;
    __syncthreads();
    for (int d = 1; d < 256; d <<= 1) {
      int x = 0;
      if (t < 256 && t >= d) x = scn[t - d];
      __syncthreads();
      if (t < 256) scn[t] += x;
      __syncthreads();
    }
    if (t < RBLK) eoff[t] = scn[t] - rcnt[t];
    __syncthreads();

    // gather this bin's edges from all regions into LDS (wave w: r ≡ w mod 8)
    const int wv = t >> 6, ln = t & 63;
    for (int r = wv; r < RBLK; r += 8) {
      const unsigned* src = binbuf + (size_t)r * EPB + roff[r];
      int c = rcnt[r], o = eoff[r];
      for (int i = ln; i < c; i += 64) ebuf[o + i] = src[i];
    }
    hist[t] = 0;
    __syncthreads();

    // count per node
    for (int i = t; i < mytotal; i += 512)
      atomicAdd(&hist[ebuf[i] >> 17], 1);
    __syncthreads();
    int v = hist[t];
    scn[t] = v;
    __syncthreads();
    for (int d = 1; d < 512; d <<= 1) {
      int x = (t >= d) ? scn[t - d] : 0;
      __syncthreads();
      scn[t] += x;
      __syncthreads();
    }
    int n = (b << BINSHIFT) + t;
    if (n < N_NODES) {
      deg[n] = v;
      offs[n] = gbase + scn[t] - v;   // segment start, dense srt
    }
    hist[t] = scn[t] - v;             // bin-local write cursor
    __syncthreads();
    for (int i = t; i < mytotal; i += 512) {
      unsigned e = ebuf[i];
      int pos = atomicAdd(&hist[e >> 17], 1);
      srt[gbase + pos] = (int)(e & 0x1FFFFu);
    }
    return;
  }
  if (b < MID_SORT_BLOCKS + MID_W_BLOCKS) {
    int bb = b - MID_SORT_BLOCKS;
    const float* W = (bb & 4) ? W2 : W1;
    unsigned short* img = Wimg + ((bb & 4) ? 128 * PADK : 0);
    int k0 = (bb & 3) * 32;
#pragma unroll
    for (int it = 0; it < 8; ++it) {
      int idx = it * 512 + t;                 // 4096 entries: 32 k x 128 n
      int k = k0 + (idx >> 7), n = idx & 127;
      img[n * PADK + k] = f2bf(W[k * 128 + n]);
    }
    return;
  }
  // ---- X f32 -> bf16 ----
  size_t i = ((size_t)(b - MID_SORT_BLOCKS - MID_W_BLOCKS) * 512 + t) * 8;
  const float4* p = (const float4*)(X + i);
  float4 a = p[0], c = p[1];
  short8 s;
  s[0] = f2bf(a.x); s[1] = f2bf(a.y); s[2] = f2bf(a.z); s[3] = f2bf(a.w);
  s[4] = f2bf(c.x); s[5] = f2bf(c.y); s[6] = f2bf(c.z); s[7] = f2bf(c.w);
  *(short8*)(Xb + i) = s;
}

// ------------- aggregation (bf16, START-semantics offs), 8-deep unroll ------
__global__ void k_gather_bf(const unsigned int* __restrict__ X1,
                            const int* __restrict__ deg, const int* __restrict__ offs,
                            const int* __restrict__ srt, unsigned int* __restrict__ h0) {
  int node = blockIdx.x * 4 + (threadIdx.x >> 6);
  int lane = threadIdx.x & 63;
  unsigned u = X1[(size_t)node * 64 + lane];
  float hx = bflo(u), hy = bfhi(u);
  int e = offs[node];
  int end = e + deg[node];
  for (; e + 8 <= end; e += 8) {
    int s0 = srt[e],     s1 = srt[e + 1], s2 = srt[e + 2], s3 = srt[e + 3];
    int s4 = srt[e + 4], s5 = srt[e + 5], s6 = srt[e + 6], s7 = srt[e + 7];
    unsigned u0 = X1[(size_t)s0 * 64 + lane];
    unsigned u1 = X1[(size_t)s1 * 64 + lane];
    unsigned u2 = X1[(size_t)s2 * 64 + lane];
    unsigned u3 = X1[(size_t)s3 * 64 + lane];
    unsigned u4 = X1[(size_t)s4 * 64 + lane];
    unsigned u5 = X1[(size_t)s5 * 64 + lane];
    unsigned u6 = X1[(size_t)s6 * 64 + lane];
    unsigned u7 = X1[(size_t)s7 * 64 + lane];
    hx += bflo(u0); hy += bfhi(u0);
    hx += bflo(u1); hy += bfhi(u1);
    hx += bflo(u2); hy += bfhi(u2);
    hx += bflo(u3); hy += bfhi(u3);
    hx += bflo(u4); hy += bfhi(u4);
    hx += bflo(u5); hy += bfhi(u5);
    hx += bflo(u6); hy += bfhi(u6);
    hx += bflo(u7); hy += bfhi(u7);
  }
  for (; e + 2 <= end; e += 2) {
    unsigned u0 = X1[(size_t)srt[e] * 64 + lane];
    unsigned u1 = X1[(size_t)srt[e + 1] * 64 + lane];
    hx += bflo(u0); hy += bfhi(u0);
    hx += bflo(u1); hy += bfhi(u1);
  }
  for (; e < end; ++e) {
    unsigned u0 = X1[(size_t)srt[e] * 64 + lane];
    hx += bflo(u0); hy += bfhi(u0);
  }
  h0[(size_t)node * 64 + lane] = ((unsigned)f2bf(hy) << 16) | f2bf(hx);
}

// ============ k_mlp2: BR=128, 8 waves (wave owns 16 rows), 2 blocks/CU ======
// (round-7 proven version) W1 staged in LDS; restage W2 after GEMM1.
#define BR2 128

__launch_bounds__(512, 4)
__global__ void k_mlp2(const unsigned short* __restrict__ h0,
                       const unsigned short* __restrict__ Wimg,
                       const float* __restrict__ b1v, const float* __restrict__ b2v,
                       float* __restrict__ out) {
  __shared__ __attribute__((aligned(16))) unsigned short lW[128 * PADK];
  __shared__ __attribute__((aligned(16))) unsigned short lH[BR2 * PADK];

  const int t = threadIdx.x;
  const int wave = t >> 6, lane = t & 63;
  const int lr = lane & 15, lg = lane >> 4;
  const int row0 = blockIdx.x * BR2;
  const int wrow = row0 + wave * 16;

  const uint4* wi = (const uint4*)Wimg;
  uint4* lw = (uint4*)lW;

  // stage W1 image (2176 uint4)
  for (int i = t; i < 2176; i += 512) lw[i] = wi[i];

  // A fragments from global bf16 h0
  bf16x8 a[4];
#pragma unroll
  for (int kb = 0; kb < 4; ++kb) {
    int r = wrow + lr;
    if (r >= N_NODES) r = N_NODES - 1;          // clamp; result unused
    a[kb] = __builtin_bit_cast(bf16x8,
        *(const short8*)(h0 + (size_t)r * D + kb * 32 + lg * 8));
  }

  f32x4 acc[8];
#pragma unroll
  for (int nc = 0; nc < 8; ++nc) {
    float bb = b1v[nc * 16 + lr];
    acc[nc] = (f32x4){bb, bb, bb, bb};
  }

  __syncthreads();   // W1 staged

  // GEMM1
#pragma unroll
  for (int nc = 0; nc < 8; ++nc) {
#pragma unroll
    for (int kb = 0; kb < 4; ++kb) {
      bf16x8 b = *(const bf16x8*)&lW[(nc * 16 + lr) * PADK + kb * 32 + lg * 8];
      acc[nc] = __builtin_amdgcn_mfma_f32_16x16x32_bf16(a[kb], b, acc[nc], 0, 0, 0);
    }
  }

  __syncthreads();   // everyone done reading W1

  // restage W2
  {
    const uint4* wi2 = (const uint4*)Wimg + 2176;
    for (int i = t; i < 2176; i += 512) lw[i] = wi2[i];
  }

  // ReLU -> h1 into own stripe (intra-wave dependency only)
#pragma unroll
  for (int nc = 0; nc < 8; ++nc) {
#pragma unroll
    for (int r = 0; r < 4; ++r) {
      float v = acc[nc][r];
      v = v > 0.f ? v : 0.f;
      lH[(wave * 16 + lg * 4 + r) * PADK + nc * 16 + lr] = f2bf(v);
    }
  }

  __syncthreads();   // W2 staged

  bf16x8 a2[4];
#pragma unroll
  for (int kb = 0; kb < 4; ++kb)
    a2[kb] = *(const bf16x8*)&lH[(wave * 16 + lr) * PADK + kb * 32 + lg * 8];

#pragma unroll
  for (int nc = 0; nc < 8; ++nc) {
    float bb = b2v[nc * 16 + lr];
    acc[nc] = (f32x4){bb, bb, bb, bb};
  }

  // GEMM2
#pragma unroll
  for (int nc = 0; nc < 8; ++nc) {
#pragma unroll
    for (int kb = 0; kb < 4; ++kb) {
      bf16x8 b = *(const bf16x8*)&lW[(nc * 16 + lr) * PADK + kb * 32 + lg * 8];
      acc[nc] = __builtin_amdgcn_mfma_f32_16x16x32_bf16(a2[kb], b, acc[nc], 0, 0, 0);
    }
  }

  // store f32
#pragma unroll
  for (int nc = 0; nc < 8; ++nc) {
#pragma unroll
    for (int r = 0; r < 4; ++r) {
      int row = wrow + lg * 4 + r;
      if (row < N_NODES) out[(size_t)row * D + nc * 16 + lr] = acc[nc][r];
    }
  }
}

// ================= old CSR build (fallback path, end-semantics offs) ========

__global__ void k_hist(const int* __restrict__ dst, int* __restrict__ deg) {
  int i = blockIdx.x * 256 + threadIdx.x;
  if (i < N_EDGES) atomicAdd(&deg[dst[i]], 1);
}

__global__ void k_scan1(const int* __restrict__ deg, int* __restrict__ offs,
                        int* __restrict__ bsum) {
  __shared__ int s[1024];
  int t = threadIdx.x;
  int i = blockIdx.x * 1024 + t;
  int v = (i < N_NODES) ? deg[i] : 0;
  s[t] = v;
  __syncthreads();
  for (int d = 1; d < 1024; d <<= 1) {
    int x = (t >= d) ? s[t - d] : 0;
    __syncthreads();
    s[t] += x;
    __syncthreads();
  }
  if (i < N_NODES) offs[i] = s[t] - v;
  if (t == 1023) bsum[blockIdx.x] = s[t];
}

__global__ void k_scan2(int* __restrict__ bsum) {
  __shared__ int s[128];
  int t = threadIdx.x;
  int v = (t < 98) ? bsum[t] : 0;
  s[t] = v;
  __syncthreads();
  for (int d = 1; d < 128; d <<= 1) {
    int x = (t >= d) ? s[t - d] : 0;
    __syncthreads();
    s[t] += x;
    __syncthreads();
  }
  if (t < 98) bsum[t] = s[t] - v;
}

__global__ void k_scan3(int* __restrict__ offs, const int* __restrict__ bsum) {
  int i = blockIdx.x * 1024 + threadIdx.x;
  if (i < N_NODES) offs[i] += bsum[blockIdx.x];
}

__global__ void k_bucket(const int* __restrict__ src, const int* __restrict__ dst,
                         int* __restrict__ offs, int* __restrict__ srt) {
  int i = blockIdx.x * 256 + threadIdx.x;
  if (i < N_EDGES) {
    int pos = atomicAdd(&offs[dst[i]], 1);
    srt[pos] = src[i];
  }
}

// ------------- f32 fallback gather (END-semantics offs) -------------
__global__ void k_gather(const float* __restrict__ X, const int* __restrict__ deg,
                         const int* __restrict__ offs, const int* __restrict__ srt,
                         float* __restrict__ out) {
  int node = blockIdx.x * 4 + (threadIdx.x >> 6);
  int lane = threadIdx.x & 63;
  const float2* X2 = (const float2*)X;
  float2 h = X2[(size_t)node * 64 + lane];
  int end = offs[node];
  int dg = deg[node];
  for (int e = end - dg; e < end; ++e) {
    int s = srt[e];
    float2 x = X2[(size_t)s * 64 + lane];
    h.x += x.x; h.y += x.y;
  }
  ((float2*)out)[(size_t)node * 64 + lane] = h;
}

// ------------- fallback fused MLP (f32 h0 in d_out, in-place) -------------
#define BR 256

__launch_bounds__(512, 1)
__global__ void k_mlp(const float* __restrict__ h0,
                      const float* __restrict__ W1, const float* __restrict__ b1,
                      const float* __restrict__ W2, const float* __restrict__ b2,
                      float* __restrict__ out) {
  __shared__ __attribute__((aligned(16))) unsigned short lW[2 * 128 * PADK];
  __shared__ __attribute__((aligned(16))) unsigned short lH[BR * PADK];

  const int t = threadIdx.x;
  const int wave = t >> 6, lane = t & 63;
  const int lr = lane & 15, lg = lane >> 4;
  const int row0 = blockIdx.x * BR;
  const int wrow = row0 + wave * 32;

  for (int i = t; i < 128 * 128; i += 512) {
    int k = i >> 7, n = i & 127;
    lW[n * PADK + k] = f2bf(W1[i]);
    lW[128 * PADK + n * PADK + k] = f2bf(W2[i]);
  }

  bf16x8 a[2][4];
#pragma unroll
  for (int tr = 0; tr < 2; ++tr) {
#pragma unroll
    for (int kb = 0; kb < 4; ++kb) {
      int r = wrow + tr * 16 + lr;
      if (r >= N_NODES) r = N_NODES - 1;
      const float4* p = (const float4*)(h0 + (size_t)r * D + kb * 32 + lg * 8);
      float4 f0 = p[0], f1 = p[1];
      short8 s;
      s[0] = f2bf(f0.x); s[1] = f2bf(f0.y); s[2] = f2bf(f0.z); s[3] = f2bf(f0.w);
      s[4] = f2bf(f1.x); s[5] = f2bf(f1.y); s[6] = f2bf(f1.z); s[7] = f2bf(f1.w);
      a[tr][kb] = __builtin_bit_cast(bf16x8, s);
    }
  }

  f32x4 acc[2][8];
#pragma unroll
  for (int nc = 0; nc < 8; ++nc) {
    float bb = b1[nc * 16 + lr];
#pragma unroll
    for (int tr = 0; tr < 2; ++tr) acc[tr][nc] = (f32x4){bb, bb, bb, bb};
  }

  __syncthreads();

#pragma unroll
  for (int nc = 0; nc < 8; ++nc) {
#pragma unroll
    for (int kb = 0; kb < 4; ++kb) {
      bf16x8 b = *(const bf16x8*)&lW[(nc * 16 + lr) * PADK + kb * 32 + lg * 8];
#pragma unroll
      for (int tr = 0; tr < 2; ++tr)
        acc[tr][nc] = __builtin_amdgcn_mfma_f32_16x16x32_bf16(a[tr][kb], b, acc[tr][nc], 0, 0, 0);
    }
  }

#pragma unroll
  for (int tr = 0; tr < 2; ++tr) {
#pragma unroll
    for (int nc = 0; nc < 8; ++nc) {
#pragma unroll
      for (int r = 0; r < 4; ++r) {
        float v = acc[tr][nc][r];
        v = v > 0.f ? v : 0.f;
        int lrow = wave * 32 + tr * 16 + lg * 4 + r;
        lH[lrow * PADK + nc * 16 + lr] = f2bf(v);
      }
    }
  }

  __syncthreads();

  bf16x8 a2[2][4];
#pragma unroll
  for (int tr = 0; tr < 2; ++tr) {
#pragma unroll
    for (int kb = 0; kb < 4; ++kb)
      a2[tr][kb] = *(const bf16x8*)&lH[(wave * 32 + tr * 16 + lr) * PADK + kb * 32 + lg * 8];
  }

#pragma unroll
  for (int nc = 0; nc < 8; ++nc) {
    float bb = b2[nc * 16 + lr];
#pragma unroll
    for (int tr = 0; tr < 2; ++tr) acc[tr][nc] = (f32x4){bb, bb, bb, bb};
  }

#pragma unroll
  for (int nc = 0; nc < 8; ++nc) {
#pragma unroll
    for (int kb = 0; kb < 4; ++kb) {
      bf16x8 b = *(const bf16x8*)&lW[128 * PADK + (nc * 16 + lr) * PADK + kb * 32 + lg * 8];
#pragma unroll
      for (int tr = 0; tr < 2; ++tr)
        acc[tr][nc] = __builtin_amdgcn_mfma_f32_16x16x32_bf16(a2[tr][kb], b, acc[tr][nc], 0, 0, 0);
    }
  }

#pragma unroll
  for (int tr = 0; tr < 2; ++tr) {
#pragma unroll
    for (int nc = 0; nc < 8; ++nc) {
#pragma unroll
      for (int r = 0; r < 4; ++r) {
        int row = wrow + tr * 16 + lg * 4 + r;
        if (row < N_NODES) out[(size_t)row * D + nc * 16 + lr] = acc[tr][nc][r];
      }
    }
  }
}

extern "C" void kernel_launch(void* const* d_in, const int* in_sizes, int n_in,
                              void* d_out, int out_size, void* d_ws, size_t ws_size,
                              hipStream_t stream) {
  const float* X  = (const float*)d_in[0];
  const float* W1 = (const float*)d_in[1];
  const float* b1 = (const float*)d_in[2];
  const float* W2 = (const float*)d_in[3];
  const float* b2 = (const float*)d_in[4];
  const int* esrc = (const int*)d_in[5];
  const int* edst = (const int*)d_in[6];
  float* out = (float*)d_out;

  char* ws = (char*)d_ws;
  // primary layout (NEED = 58,469,632 <= proven 58,471,680 budget)
  int* deg      = (int*)(ws);                          // 400,000 B
  int* offs     = (int*)(ws + 400000);                 // 400,000 B
  int* srt      = (int*)(ws + 800000);                 // 6,400,000 B -> 7,200,000
  unsigned short* Xb  = (unsigned short*)(ws + 7200000);   // 25.6 MB -> 32,800,000
  unsigned short* h0b = (unsigned short*)(ws + 32800000);  // 25.6 MB -> 58,400,000
  // aliases inside h0b (all dead before gather writes h0b):
  unsigned* binbuf = (unsigned*)(ws + 32800000);           // 6,422,528 B
  int* cntmatT   = (int*)(ws + 32800000 + 6422528);        // 153,664 B
  int* startmatT = (int*)(ws + 32800000 + 6422528 + 153664); // 153,664 B
  unsigned short* Wimg = (unsigned short*)(ws + 58400000); // 69,632 B
  const size_t NEED = 58469632;

  if (ws_size >= NEED) {
    k_bin2<<<RBLK, 512, 0, stream>>>(esrc, edst, binbuf, cntmatT, startmatT);
    k_mid<<<MID_SORT_BLOCKS + MID_W_BLOCKS + MID_CVT_BLOCKS, 512, 0, stream>>>(
        binbuf, cntmatT, startmatT, srt, deg, offs, X, Xb, W1, W2, Wimg);
    k_gather_bf<<<N_NODES / 4, 256, 0, stream>>>((const unsigned*)Xb, deg, offs, srt,
                                                 (unsigned*)h0b);
    k_mlp2<<<(N_NODES + BR2 - 1) / BR2, 512, 0, stream>>>(h0b, Wimg, b1, b2, out);
  } else {
    // fallback: proven round-1 pipeline (f32 gather, END-semantics offs)
    int* bsum  = (int*)(ws + 800000);                  // 1 KB
    int* srtF  = (int*)(ws + 802048);                  // 6.4 MB
    hipMemsetAsync(deg, 0, N_NODES * sizeof(int), stream);
    k_hist  <<<N_EDGES / 256, 256, 0, stream>>>(edst, deg);
    k_scan1 <<<98, 1024, 0, stream>>>(deg, offs, bsum);
    k_scan2 <<<1, 128, 0, stream>>>(bsum);
    k_scan3 <<<98, 1024, 0, stream>>>(offs, bsum);
    k_bucket<<<N_EDGES / 256, 256, 0, stream>>>(esrc, edst, offs, srtF);
    k_gather<<<N_NODES / 4, 256, 0, stream>>>(X, deg, offs, srtF, out);
    k_mlp   <<<(N_NODES + BR - 1) / BR, 512, 0, stream>>>(out, W1, b1, W2, b2, out);
  }
}

// Round 11
// 130.465 us; speedup vs baseline: 1.0856x; 1.0142x over previous
//
#include <hip/hip_runtime.h>
#include <hip/hip_bf16.h>

#define N_NODES 100000
#define N_EDGES 1600000
#define D 128

#define NBINS 196       // ceil(100000 / 512) node bins
#define BINSHIFT 9      // 512 nodes per bin
#define EPB 8192        // edges per region (k_head bin block)
#define RBLK 196        // edge regions = ceil(N_EDGES / EPB)
#define EBUF_CAP 8960   // LDS staging cap per bin (mean 8163, ~8.8 sigma)

// k_head block layout: [0,196) bin, [196,204) W image, [204,3329) X cvt
#define HEAD_W_BLOCKS 8
#define HEAD_CVT_BLOCKS 3125   // 100000*128 / (512*8)

#define PADK 136

typedef __bf16 bf16x8 __attribute__((ext_vector_type(8)));
typedef short short8 __attribute__((ext_vector_type(8)));
typedef float f32x4 __attribute__((ext_vector_type(4)));

__device__ __forceinline__ unsigned short f2bf(float f) {
  union { float f; unsigned u; } c; c.f = f;
  unsigned u = c.u;
  u += 0x7FFFu + ((u >> 16) & 1u);   // round-to-nearest-even
  return (unsigned short)(u >> 16);
}
__device__ __forceinline__ float bflo(unsigned u) {
  union { unsigned u; float f; } c; c.u = u << 16; return c.f;
}
__device__ __forceinline__ float bfhi(unsigned u) {
  union { unsigned u; float f; } c; c.u = u & 0xFFFF0000u; return c.f;
}

// ============ k_head: fused edge binning (FIRST) + W image + X cvt ==========
// Bin blocks: LDS counting sort by coarse bin, dense 32KB stream-out into a
// private region; emits [bin][region] count/start matrices. Zero global
// atomics, zero memset. (round-10 proven k_bin2 body)
__launch_bounds__(512)
__global__ void k_head(const int* __restrict__ esrc, const int* __restrict__ edst,
                       unsigned* __restrict__ binbuf, int* __restrict__ cntmatT,
                       int* __restrict__ startmatT,
                       const float* __restrict__ X, unsigned short* __restrict__ Xb,
                       const float* __restrict__ W1, const float* __restrict__ W2,
                       unsigned short* __restrict__ Wimg) {
  const int b = blockIdx.x, t = threadIdx.x;

  if (b < RBLK) {
    __shared__ unsigned lbuf[EPB];       // 32 KB
    __shared__ int cnt[NBINS];
    __shared__ int base[NBINS];
    __shared__ int cur[NBINS];
    __shared__ int scanb[256];
    const int e0 = b * EPB;
    const int ne = min(EPB, N_EDGES - e0);

    for (int i = t; i < NBINS; i += 512) { cnt[i] = 0; cur[i] = 0; }
    __syncthreads();
    for (int i = t; i < ne; i += 512)
      atomicAdd(&cnt[edst[e0 + i] >> BINSHIFT], 1);
    __syncthreads();
    if (t < 256) scanb[t] = (t < NBINS) ? cnt[t] : 0;
    __syncthreads();
    for (int d = 1; d < 256; d <<= 1) {
      int x = 0;
      if (t < 256 && t >= d) x = scanb[t - d];
      __syncthreads();
      if (t < 256) scanb[t] += x;
      __syncthreads();
    }
    if (t < NBINS) base[t] = scanb[t] - cnt[t];
    __syncthreads();
    for (int i = t; i < ne; i += 512) {
      int d = edst[e0 + i];
      int s = esrc[e0 + i];
      int bi = d >> BINSHIFT;
      int pos = base[bi] + atomicAdd(&cur[bi], 1);
      lbuf[pos] = ((unsigned)(d & 511) << 17) | (unsigned)s;
    }
    __syncthreads();
    // dense stream-out (garbage tail never referenced via counts)
    uint4* dst4 = (uint4*)(binbuf + (size_t)b * EPB);
    const uint4* src4 = (const uint4*)lbuf;
    for (int i = t; i < EPB / 4; i += 512) dst4[i] = src4[i];
    if (t < NBINS) {
      cntmatT[t * RBLK + b] = cnt[t];     // [bin][region]
      startmatT[t * RBLK + b] = base[t];
    }
    return;
  }
  if (b < RBLK + HEAD_W_BLOCKS) {
    int bb = b - RBLK;
    const float* W = (bb & 4) ? W2 : W1;
    unsigned short* img = Wimg + ((bb & 4) ? 128 * PADK : 0);
    int k0 = (bb & 3) * 32;
#pragma unroll
    for (int it = 0; it < 8; ++it) {
      int idx = it * 512 + t;                 // 4096 entries: 32 k x 128 n
      int k = k0 + (idx >> 7), n = idx & 127;
      img[n * PADK + k] = f2bf(W[k * 128 + n]);
    }
    return;
  }
  // ---- X f32 -> bf16 ----
  size_t i = ((size_t)(b - RBLK - HEAD_W_BLOCKS) * 512 + t) * 8;
  const float4* p = (const float4*)(X + i);
  float4 a = p[0], c = p[1];
  short8 s;
  s[0] = f2bf(a.x); s[1] = f2bf(a.y); s[2] = f2bf(a.z); s[3] = f2bf(a.w);
  s[4] = f2bf(c.x); s[5] = f2bf(c.y); s[6] = f2bf(c.z); s[7] = f2bf(c.w);
  *(short8*)(Xb + i) = s;
}

// ============ k_sortgather: per-bin sort (LDS-resident) + gather ============
// Block b: gather its bin's edges from the 196 region chunks into ebuf,
// count/scan/scatter to per-node-sorted ebuf2 (src only), then 16 waves
// gather 32 nodes each (8-deep unrolled row reads) and write h0 bf16.
// No srt/deg/offs global round-trip at all.
__launch_bounds__(1024)
__global__ void k_sortgather(const unsigned* __restrict__ binbuf,
                             const int* __restrict__ cntmatT,
                             const int* __restrict__ startmatT,
                             const unsigned* __restrict__ X1,
                             unsigned* __restrict__ h0) {
  __shared__ unsigned ebuf[EBUF_CAP];    // 35 KB
  __shared__ unsigned ebuf2[EBUF_CAP];   // 35 KB
  __shared__ int hist[512];
  __shared__ int scn[512];
  __shared__ int nstart[512];
  __shared__ int ncnt[512];
  __shared__ int rcnt[RBLK];
  __shared__ int roff[RBLK];
  __shared__ int eoff[RBLK];
  __shared__ int s_total;

  const int b = blockIdx.x, t = threadIdx.x;
  const int n0 = b << BINSHIFT;
  const int wv = t >> 6, ln = t & 63;

  // this bin's per-region counts/starts (coalesced 784B rows)
  for (int r = t; r < RBLK; r += 1024) {
    rcnt[r] = cntmatT[b * RBLK + r];
    roff[r] = startmatT[b * RBLK + r];
  }
  __syncthreads();

  // eoff = exclusive scan of rcnt; total = edges in this bin
  if (t < 256) scn[t] = (t < RBLK) ? rcnt[t] : 0;
  __syncthreads();
  for (int d = 1; d < 256; d <<= 1) {
    int x = 0;
    if (t < 256 && t >= d) x = scn[t - d];
    __syncthreads();
    if (t < 256) scn[t] += x;
    __syncthreads();
  }
  if (t < RBLK) eoff[t] = scn[t] - rcnt[t];
  if (t == RBLK - 1) s_total = scn[t];
  __syncthreads();
  const int mytotal = s_total;

  // gather this bin's edges from all regions into LDS (wave wv: r = wv mod 16)
  for (int r = wv; r < RBLK; r += 16) {
    const unsigned* src = binbuf + (size_t)r * EPB + roff[r];
    int c = rcnt[r], o = eoff[r];
    for (int i = ln; i < c; i += 64) ebuf[o + i] = src[i];
  }
  if (t < 512) hist[t] = 0;
  __syncthreads();

  // per-node counts
  for (int i = t; i < mytotal; i += 1024)
    atomicAdd(&hist[ebuf[i] >> 17], 1);
  __syncthreads();
  int v = (t < 512) ? hist[t] : 0;
  if (t < 512) scn[t] = v;
  __syncthreads();
  for (int d = 1; d < 512; d <<= 1) {
    int x = 0;
    if (t < 512 && t >= d) x = scn[t - d];
    __syncthreads();
    if (t < 512) scn[t] += x;
    __syncthreads();
  }
  if (t < 512) {
    nstart[t] = scn[t] - v;
    ncnt[t] = v;
    hist[t] = scn[t] - v;   // write cursor
  }
  __syncthreads();
  // scatter to per-node-sorted order; keep only src (17 bits)
  for (int i = t; i < mytotal; i += 1024) {
    unsigned e = ebuf[i];
    int pos = atomicAdd(&hist[e >> 17], 1);
    ebuf2[pos] = e & 0x1FFFFu;
  }
  __syncthreads();

  // ---- gather phase: wave wv owns local nodes [wv*32, wv*32+32) ----
  for (int j = 0; j < 32; ++j) {
    int li = wv * 32 + j;
    int node = n0 + li;
    if (node >= N_NODES) break;
    unsigned u = X1[(size_t)node * 64 + ln];
    float hx = bflo(u), hy = bfhi(u);
    int e = nstart[li];
    int end = e + ncnt[li];
    for (; e + 8 <= end; e += 8) {
      int s0 = ebuf2[e],     s1 = ebuf2[e + 1], s2 = ebuf2[e + 2], s3 = ebuf2[e + 3];
      int s4 = ebuf2[e + 4], s5 = ebuf2[e + 5], s6 = ebuf2[e + 6], s7 = ebuf2[e + 7];
      unsigned u0 = X1[(size_t)s0 * 64 + ln];
      unsigned u1 = X1[(size_t)s1 * 64 + ln];
      unsigned u2 = X1[(size_t)s2 * 64 + ln];
      unsigned u3 = X1[(size_t)s3 * 64 + ln];
      unsigned u4 = X1[(size_t)s4 * 64 + ln];
      unsigned u5 = X1[(size_t)s5 * 64 + ln];
      unsigned u6 = X1[(size_t)s6 * 64 + ln];
      unsigned u7 = X1[(size_t)s7 * 64 + ln];
      hx += bflo(u0); hy += bfhi(u0);
      hx += bflo(u1); hy += bfhi(u1);
      hx += bflo(u2); hy += bfhi(u2);
      hx += bflo(u3); hy += bfhi(u3);
      hx += bflo(u4); hy += bfhi(u4);
      hx += bflo(u5); hy += bfhi(u5);
      hx += bflo(u6); hy += bfhi(u6);
      hx += bflo(u7); hy += bfhi(u7);
    }
    for (; e + 2 <= end; e += 2) {
      unsigned u0 = X1[(size_t)ebuf2[e] * 64 + ln];
      unsigned u1 = X1[(size_t)ebuf2[e + 1] * 64 + ln];
      hx += bflo(u0); hy += bfhi(u0);
      hx += bflo(u1); hy += bfhi(u1);
    }
    for (; e < end; ++e) {
      unsigned u0 = X1[(size_t)ebuf2[e] * 64 + ln];
      hx += bflo(u0); hy += bfhi(u0);
    }
    h0[(size_t)node * 64 + ln] = ((unsigned)f2bf(hy) << 16) | f2bf(hx);
  }
}

// ============ k_mlp2: BR=128, 8 waves (wave owns 16 rows), 2 blocks/CU ======
// (round-7/10 proven) W1 staged in LDS; restage W2 after GEMM1.
#define BR2 128

__launch_bounds__(512, 4)
__global__ void k_mlp2(const unsigned short* __restrict__ h0,
                       const unsigned short* __restrict__ Wimg,
                       const float* __restrict__ b1v, const float* __restrict__ b2v,
                       float* __restrict__ out) {
  __shared__ __attribute__((aligned(16))) unsigned short lW[128 * PADK];
  __shared__ __attribute__((aligned(16))) unsigned short lH[BR2 * PADK];

  const int t = threadIdx.x;
  const int wave = t >> 6, lane = t & 63;
  const int lr = lane & 15, lg = lane >> 4;
  const int row0 = blockIdx.x * BR2;
  const int wrow = row0 + wave * 16;

  const uint4* wi = (const uint4*)Wimg;
  uint4* lw = (uint4*)lW;

  // stage W1 image (2176 uint4)
  for (int i = t; i < 2176; i += 512) lw[i] = wi[i];

  // A fragments from global bf16 h0
  bf16x8 a[4];
#pragma unroll
  for (int kb = 0; kb < 4; ++kb) {
    int r = wrow + lr;
    if (r >= N_NODES) r = N_NODES - 1;          // clamp; result unused
    a[kb] = __builtin_bit_cast(bf16x8,
        *(const short8*)(h0 + (size_t)r * D + kb * 32 + lg * 8));
  }

  f32x4 acc[8];
#pragma unroll
  for (int nc = 0; nc < 8; ++nc) {
    float bb = b1v[nc * 16 + lr];
    acc[nc] = (f32x4){bb, bb, bb, bb};
  }

  __syncthreads();   // W1 staged

  // GEMM1
#pragma unroll
  for (int nc = 0; nc < 8; ++nc) {
#pragma unroll
    for (int kb = 0; kb < 4; ++kb) {
      bf16x8 b = *(const bf16x8*)&lW[(nc * 16 + lr) * PADK + kb * 32 + lg * 8];
      acc[nc] = __builtin_amdgcn_mfma_f32_16x16x32_bf16(a[kb], b, acc[nc], 0, 0, 0);
    }
  }

  __syncthreads();   // everyone done reading W1

  // restage W2
  {
    const uint4* wi2 = (const uint4*)Wimg + 2176;
    for (int i = t; i < 2176; i += 512) lw[i] = wi2[i];
  }

  // ReLU -> h1 into own stripe (intra-wave dependency only)
#pragma unroll
  for (int nc = 0; nc < 8; ++nc) {
#pragma unroll
    for (int r = 0; r < 4; ++r) {
      float v = acc[nc][r];
      v = v > 0.f ? v : 0.f;
      lH[(wave * 16 + lg * 4 + r) * PADK + nc * 16 + lr] = f2bf(v);
    }
  }

  __syncthreads();   // W2 staged

  bf16x8 a2[4];
#pragma unroll
  for (int kb = 0; kb < 4; ++kb)
    a2[kb] = *(const bf16x8*)&lH[(wave * 16 + lr) * PADK + kb * 32 + lg * 8];

#pragma unroll
  for (int nc = 0; nc < 8; ++nc) {
    float bb = b2v[nc * 16 + lr];
    acc[nc] = (f32x4){bb, bb, bb, bb};
  }

  // GEMM2
#pragma unroll
  for (int nc = 0; nc < 8; ++nc) {
#pragma unroll
    for (int kb = 0; kb < 4; ++kb) {
      bf16x8 b = *(const bf16x8*)&lW[(nc * 16 + lr) * PADK + kb * 32 + lg * 8];
      acc[nc] = __builtin_amdgcn_mfma_f32_16x16x32_bf16(a2[kb], b, acc[nc], 0, 0, 0);
    }
  }

  // store f32
#pragma unroll
  for (int nc = 0; nc < 8; ++nc) {
#pragma unroll
    for (int r = 0; r < 4; ++r) {
      int row = wrow + lg * 4 + r;
      if (row < N_NODES) out[(size_t)row * D + nc * 16 + lr] = acc[nc][r];
    }
  }
}

// ================= old CSR build (fallback path, end-semantics offs) ========

__global__ void k_hist(const int* __restrict__ dst, int* __restrict__ deg) {
  int i = blockIdx.x * 256 + threadIdx.x;
  if (i < N_EDGES) atomicAdd(&deg[dst[i]], 1);
}

__global__ void k_scan1(const int* __restrict__ deg, int* __restrict__ offs,
                        int* __restrict__ bsum) {
  __shared__ int s[1024];
  int t = threadIdx.x;
  int i = blockIdx.x * 1024 + t;
  int v = (i < N_NODES) ? deg[i] : 0;
  s[t] = v;
  __syncthreads();
  for (int d = 1; d < 1024; d <<= 1) {
    int x = (t >= d) ? s[t - d] : 0;
    __syncthreads();
    s[t] += x;
    __syncthreads();
  }
  if (i < N_NODES) offs[i] = s[t] - v;
  if (t == 1023) bsum[blockIdx.x] = s[t];
}

__global__ void k_scan2(int* __restrict__ bsum) {
  __shared__ int s[128];
  int t = threadIdx.x;
  int v = (t < 98) ? bsum[t] : 0;
  s[t] = v;
  __syncthreads();
  for (int d = 1; d < 128; d <<= 1) {
    int x = (t >= d) ? s[t - d] : 0;
    __syncthreads();
    s[t] += x;
    __syncthreads();
  }
  if (t < 98) bsum[t] = s[t] - v;
}

__global__ void k_scan3(int* __restrict__ offs, const int* __restrict__ bsum) {
  int i = blockIdx.x * 1024 + threadIdx.x;
  if (i < N_NODES) offs[i] += bsum[blockIdx.x];
}

__global__ void k_bucket(const int* __restrict__ src, const int* __restrict__ dst,
                         int* __restrict__ offs, int* __restrict__ srt) {
  int i = blockIdx.x * 256 + threadIdx.x;
  if (i < N_EDGES) {
    int pos = atomicAdd(&offs[dst[i]], 1);
    srt[pos] = src[i];
  }
}

// ------------- f32 fallback gather (END-semantics offs) -------------
__global__ void k_gather(const float* __restrict__ X, const int* __restrict__ deg,
                         const int* __restrict__ offs, const int* __restrict__ srt,
                         float* __restrict__ out) {
  int node = blockIdx.x * 4 + (threadIdx.x >> 6);
  int lane = threadIdx.x & 63;
  const float2* X2 = (const float2*)X;
  float2 h = X2[(size_t)node * 64 + lane];
  int end = offs[node];
  int dg = deg[node];
  for (int e = end - dg; e < end; ++e) {
    int s = srt[e];
    float2 x = X2[(size_t)s * 64 + lane];
    h.x += x.x; h.y += x.y;
  }
  ((float2*)out)[(size_t)node * 64 + lane] = h;
}

// ------------- fallback fused MLP (f32 h0 in d_out, in-place) -------------
#define BR 256

__launch_bounds__(512, 1)
__global__ void k_mlp(const float* __restrict__ h0,
                      const float* __restrict__ W1, const float* __restrict__ b1,
                      const float* __restrict__ W2, const float* __restrict__ b2,
                      float* __restrict__ out) {
  __shared__ __attribute__((aligned(16))) unsigned short lW[2 * 128 * PADK];
  __shared__ __attribute__((aligned(16))) unsigned short lH[BR * PADK];

  const int t = threadIdx.x;
  const int wave = t >> 6, lane = t & 63;
  const int lr = lane & 15, lg = lane >> 4;
  const int row0 = blockIdx.x * BR;
  const int wrow = row0 + wave * 32;

  for (int i = t; i < 128 * 128; i += 512) {
    int k = i >> 7, n = i & 127;
    lW[n * PADK + k] = f2bf(W1[i]);
    lW[128 * PADK + n * PADK + k] = f2bf(W2[i]);
  }

  bf16x8 a[2][4];
#pragma unroll
  for (int tr = 0; tr < 2; ++tr) {
#pragma unroll
    for (int kb = 0; kb < 4; ++kb) {
      int r = wrow + tr * 16 + lr;
      if (r >= N_NODES) r = N_NODES - 1;
      const float4* p = (const float4*)(h0 + (size_t)r * D + kb * 32 + lg * 8);
      float4 f0 = p[0], f1 = p[1];
      short8 s;
      s[0] = f2bf(f0.x); s[1] = f2bf(f0.y); s[2] = f2bf(f0.z); s[3] = f2bf(f0.w);
      s[4] = f2bf(f1.x); s[5] = f2bf(f1.y); s[6] = f2bf(f1.z); s[7] = f2bf(f1.w);
      a[tr][kb] = __builtin_bit_cast(bf16x8, s);
    }
  }

  f32x4 acc[2][8];
#pragma unroll
  for (int nc = 0; nc < 8; ++nc) {
    float bb = b1[nc * 16 + lr];
#pragma unroll
    for (int tr = 0; tr < 2; ++tr) acc[tr][nc] = (f32x4){bb, bb, bb, bb};
  }

  __syncthreads();

#pragma unroll
  for (int nc = 0; nc < 8; ++nc) {
#pragma unroll
    for (int kb = 0; kb < 4; ++kb) {
      bf16x8 b = *(const bf16x8*)&lW[(nc * 16 + lr) * PADK + kb * 32 + lg * 8];
#pragma unroll
      for (int tr = 0; tr < 2; ++tr)
        acc[tr][nc] = __builtin_amdgcn_mfma_f32_16x16x32_bf16(a[tr][kb], b, acc[tr][nc], 0, 0, 0);
    }
  }

#pragma unroll
  for (int tr = 0; tr < 2; ++tr) {
#pragma unroll
    for (int nc = 0; nc < 8; ++nc) {
#pragma unroll
      for (int r = 0; r < 4; ++r) {
        float v = acc[tr][nc][r];
        v = v > 0.f ? v : 0.f;
        int lrow = wave * 32 + tr * 16 + lg * 4 + r;
        lH[lrow * PADK + nc * 16 + lr] = f2bf(v);
      }
    }
  }

  __syncthreads();

  bf16x8 a2[2][4];
#pragma unroll
  for (int tr = 0; tr < 2; ++tr) {
#pragma unroll
    for (int kb = 0; kb < 4; ++kb)
      a2[tr][kb] = *(const bf16x8*)&lH[(wave * 32 + tr * 16 + lr) * PADK + kb * 32 + lg * 8];
  }

#pragma unroll
  for (int nc = 0; nc < 8; ++nc) {
    float bb = b2[nc * 16 + lr];
#pragma unroll
    for (int tr = 0; tr < 2; ++tr) acc[tr][nc] = (f32x4){bb, bb, bb, bb};
  }

#pragma unroll
  for (int nc = 0; nc < 8; ++nc) {
#pragma unroll
    for (int kb = 0; kb < 4; ++kb) {
      bf16x8 b = *(const bf16x8*)&lW[128 * PADK + (nc * 16 + lr) * PADK + kb * 32 + lg * 8];
#pragma unroll
      for (int tr = 0; tr < 2; ++tr)
        acc[tr][nc] = __builtin_amdgcn_mfma_f32_16x16x32_bf16(a2[tr][kb], b, acc[tr][nc], 0, 0, 0);
    }
  }

#pragma unroll
  for (int tr = 0; tr < 2; ++tr) {
#pragma unroll
    for (int nc = 0; nc < 8; ++nc) {
#pragma unroll
      for (int r = 0; r < 4; ++r) {
        int row = wrow + tr * 16 + lg * 4 + r;
        if (row < N_NODES) out[(size_t)row * D + nc * 16 + lr] = acc[tr][nc][r];
      }
    }
  }
}

extern "C" void kernel_launch(void* const* d_in, const int* in_sizes, int n_in,
                              void* d_out, int out_size, void* d_ws, size_t ws_size,
                              hipStream_t stream) {
  const float* X  = (const float*)d_in[0];
  const float* W1 = (const float*)d_in[1];
  const float* b1 = (const float*)d_in[2];
  const float* W2 = (const float*)d_in[3];
  const float* b2 = (const float*)d_in[4];
  const int* esrc = (const int*)d_in[5];
  const int* edst = (const int*)d_in[6];
  float* out = (float*)d_out;

  char* ws = (char*)d_ws;
  // primary layout — NO aliasing (sortgather reads binbuf & writes h0b in
  // the same kernel). NEED = 57,999,488 <= proven 58,471,680 budget.
  unsigned* binbuf = (unsigned*)(ws);                        // 6,422,528 B
  int* cntmatT   = (int*)(ws + 6422528);                     // 153,664 B
  int* startmatT = (int*)(ws + 6576192);                     // 153,664 B
  unsigned short* Xb  = (unsigned short*)(ws + 6729856);     // 25.6 MB
  unsigned short* h0b = (unsigned short*)(ws + 32329856);    // 25.6 MB
  unsigned short* Wimg = (unsigned short*)(ws + 57929856);   // 69,632 B
  const size_t NEED = 57999488;

  if (ws_size >= NEED) {
    k_head<<<RBLK + HEAD_W_BLOCKS + HEAD_CVT_BLOCKS, 512, 0, stream>>>(
        esrc, edst, binbuf, cntmatT, startmatT, X, Xb, W1, W2, Wimg);
    k_sortgather<<<NBINS, 1024, 0, stream>>>(binbuf, cntmatT, startmatT,
                                             (const unsigned*)Xb, (unsigned*)h0b);
    k_mlp2<<<(N_NODES + BR2 - 1) / BR2, 512, 0, stream>>>(h0b, Wimg, b1, b2, out);
  } else {
    // fallback: proven round-1 pipeline (f32 gather, END-semantics offs)
    int* deg  = (int*)(ws);                    // 400,000 B
    int* offs = (int*)(ws + 400000);           // 400,000 B
    int* bsum = (int*)(ws + 800000);           // 1 KB
    int* srtF = (int*)(ws + 802048);           // 6.4 MB
    hipMemsetAsync(deg, 0, N_NODES * sizeof(int), stream);
    k_hist  <<<N_EDGES / 256, 256, 0, stream>>>(edst, deg);
    k_scan1 <<<98, 1024, 0, stream>>>(deg, offs, bsum);
    k_scan2 <<<1, 128, 0, stream>>>(bsum);
    k_scan3 <<<98, 1024, 0, stream>>>(offs, bsum);
    k_bucket<<<N_EDGES / 256, 256, 0, stream>>>(esrc, edst, offs, srtF);
    k_gather<<<N_NODES / 4, 256, 0, stream>>>(X, deg, offs, srtF, out);
    k_mlp   <<<(N_NODES + BR - 1) / BR, 512, 0, stream>>>(out, W1, b1, W2, b2, out);
  }
}